// Round 13
// baseline (5975.274 us; speedup 1.0000x reference)
//
#include <hip/hip_runtime.h>
#include <hip/hip_bf16.h>

typedef __attribute__((ext_vector_type(8))) short bf16x8;
typedef __attribute__((ext_vector_type(4))) float f32x4;
typedef __hip_bfloat16 bf16;

#define ALPHA_F 0.42728713f
#define LN_EPS 1e-3f

__device__ __forceinline__ float silu_f(float x) { return x / (1.0f + __expf(-x)); }
// mish(x) = x*tanh(ln(1+e^x)) = x*(t^2-1)/(t^2+1), t=1+e^x  (exact rewrite, no tanh/log1p)
__device__ __forceinline__ float mish_f(float x) {
  if (x > 20.0f) return x;
  float t = 1.0f + __expf(x);
  float t2 = t * t;
  return x * (t2 - 1.0f) / (t2 + 1.0f);
}
__device__ __forceinline__ unsigned short f2bfu(float x) {
  bf16 h = __float2bfloat16(x);
  return *(unsigned short*)&h;
}
__device__ __forceinline__ float bfu2f(unsigned short u) {
  unsigned int v = (unsigned int)u << 16;
  return *(float*)&v;
}

// Builtin MFMA: LLVM sees real dataflow -> acc lives in AGPRs.
#define MFMA16(acc, a, b) \
  (acc) = __builtin_amdgcn_mfma_f32_16x16x32_bf16((a), (b), (acc), 0, 0, 0)

#define GLOAD_LDS16(gp, lp)                                                              \
  __builtin_amdgcn_global_load_lds((__attribute__((address_space(1))) void*)(void*)(gp), \
                                   (__attribute__((address_space(3))) void*)(void*)(lp), \
                                   16, 0, 0)

// ---------------- batched per-layer weight transpose: W[K,N] f32 -> Wt[N,K] bf16 -------
__global__ __launch_bounds__(256) void transpose_layer(
    const float* __restrict__ wq, const float* __restrict__ wk, const float* __restrict__ wv,
    const float* __restrict__ wo, const float* __restrict__ f1, const float* __restrict__ f2,
    const float* __restrict__ sgf, const float* __restrict__ swg, const float* __restrict__ sh1,
    const float* __restrict__ scw,
    bf16* __restrict__ Wqkv, bf16* __restrict__ Wo, bf16* __restrict__ Wf1,
    bf16* __restrict__ Wf2, bf16* __restrict__ Wsgf, bf16* __restrict__ Wswg,
    bf16* __restrict__ Wsh1, bf16* __restrict__ Wsc) {
  __shared__ float tile[32][33];
  int b = blockIdx.x;
  const float* W;
  bf16* Wt;
  int K, N, tb;
  if (b < 3072) {
    int m = b >> 10;
    W = (m == 0) ? wq : ((m == 1) ? wk : wv);
    Wt = Wqkv + (size_t)m * 1024 * 1024;
    K = 1024; N = 1024; tb = b & 1023;
  } else if (b < 4096)  { W = wo;  Wt = Wo;   K = 1024; N = 1024; tb = b - 3072; }
  else if (b < 5632)    { W = f1;  Wt = Wf1;  K = 1024; N = 1536; tb = b - 4096; }
  else if (b < 7168)    { W = f2;  Wt = Wf2;  K = 1536; N = 1024; tb = b - 5632; }
  else if (b < 9216)    { W = sgf; Wt = Wsgf; K = 256;  N = 8192; tb = b - 7168; }
  else if (b < 10240)   { W = swg; Wt = Wswg; K = 256;  N = 4096; tb = b - 9216; }
  else if (b < 10752)   { W = sh1; Wt = Wsh1; K = 2048; N = 256;  tb = b - 10240; }
  else                  { W = scw; Wt = Wsc;  K = 1024; N = 32;   tb = b - 10752; }
  int ntx = N >> 5;
  int ty_ = tb / ntx, tx_ = tb - ty_ * ntx;
  int nb = tx_ * 32, kb = ty_ * 32;
  int tx = threadIdx.x & 31, ty = threadIdx.x >> 5;
#pragma unroll
  for (int i = 0; i < 4; ++i)
    tile[ty + i * 8][tx] = W[(size_t)(kb + ty + i * 8) * N + nb + tx];
  __syncthreads();
#pragma unroll
  for (int i = 0; i < 4; ++i)
    Wt[(size_t)(nb + ty + i * 8) * K + kb + tx] = __float2bfloat16(tile[tx][ty + i * 8]);
}

__global__ __launch_bounds__(256) void cvt_f32_bf16_k(const float* __restrict__ in,
                                                      bf16* __restrict__ out, long long n) {
  long long i = ((long long)blockIdx.x * 256 + threadIdx.x) * 4;
  if (i + 3 < n) {
    float4 v = *(const float4*)(in + i);
    out[i + 0] = __float2bfloat16(v.x);
    out[i + 1] = __float2bfloat16(v.y);
    out[i + 2] = __float2bfloat16(v.z);
    out[i + 3] = __float2bfloat16(v.w);
  }
}

__global__ __launch_bounds__(256) void pack3_k(const float* __restrict__ a,
                                               const float* __restrict__ b,
                                               const float* __restrict__ c,
                                               float* __restrict__ o) {
  int i = blockIdx.x * 256 + threadIdx.x;
  if (i < 1024) o[i] = a[i];
  else if (i < 2048) o[i] = b[i - 1024];
  else if (i < 3072) o[i] = c[i - 2048];
}

__global__ __launch_bounds__(1) void sentinel_k(float* __restrict__ o) { o[0] = 1.2345e7f; }

// ---------------- BMxBN bf16 MFMA GEMM, 2-phase double-buffered, XCD-swizzled ----------
// R10/R11/R12: GEMMs here are latency-bound; throughput ~ resident blocks/CU. 64x64
// tiles (16KB LDS) -> 8 blocks/CU (wave-capped). Used for all big-M GEMMs incl. QKV.
template <int BM, int BN, int ACT, bool OUTBF16, bool BIAS>
__global__ __launch_bounds__(256) void gemm_tn(const bf16* __restrict__ A,
                                               const bf16* __restrict__ Bt,
                                               const float* __restrict__ bias,
                                               float* __restrict__ Cf, bf16* __restrict__ Cb,
                                               int M, int N, int K) {
  constexpr int NWC = (BN == 128) ? 2 : 1;  // waves along N
  constexpr int NWR = 4 / NWC;              // waves along M
  constexpr int AR = BM / (16 * NWR);       // row frags per wave
  constexpr int AC = BN / (16 * NWC);       // col frags per wave
  __shared__ __align__(128) short As[2][BM * 32];
  __shared__ __align__(128) short Bs[2][BN * 32];
  int t = threadIdx.x;
  int lane = t & 63, wave = t >> 6;
  // bijective XCD swizzle (m204)
  int nbx = N / BN;
  int nwg = gridDim.x;
  int q = nwg >> 3, r = nwg & 7;
  int xcd = blockIdx.x & 7, lid = blockIdx.x >> 3;
  int swz = (xcd < r ? xcd * (q + 1) : r * (q + 1) + (xcd - r) * q) + lid;
  int by = swz / nbx, bx = swz - by * nbx;
  int m0 = by * BM, n0 = bx * BN;
  int wr = wave / NWC, wc = wave % NWC;
  int fr = lane & 15;
  int fk = (lane >> 4) << 3;

  f32x4 acc[AR][AC] = {};

  int row0 = t >> 2, ko0 = (t & 3) << 3;

  const bf16* Ag0 = A + (size_t)(m0 + row0) * K + ko0;
  const bf16* Ag1 = A + (size_t)(m0 + 64 + row0) * K + ko0;   // used only if BM==128
  const bf16* Bg0 = Bt + (size_t)(n0 + row0) * K + ko0;
  const bf16* Bg1 = Bt + (size_t)(n0 + 64 + row0) * K + ko0;  // used only if BN==128

  auto stageTo = [&](int buf, int k0) {
    GLOAD_LDS16(Ag0 + k0, &As[buf][wave * 512]);
    if constexpr (BM == 128) GLOAD_LDS16(Ag1 + k0, &As[buf][2048 + wave * 512]);
    GLOAD_LDS16(Bg0 + k0, &Bs[buf][wave * 512]);
    if constexpr (BN == 128) GLOAD_LDS16(Bg1 + k0, &Bs[buf][2048 + wave * 512]);
  };

  int nk = K >> 5;
  stageTo(0, 0);
  __syncthreads();  // vmcnt(0) drain: tile 0 resident

  const int rdA = (wr * (BM / NWR) + fr) * 32 + fk;
  const int rdB = (wc * (BN / NWC) + fr) * 32 + fk;

  for (int kt = 0; kt < nk; ++kt) {
    int cur = kt & 1;
    if (kt + 1 < nk) stageTo(cur ^ 1, (kt + 1) << 5);
    bf16x8 af[AR], bfv[AC];
#pragma unroll
    for (int a = 0; a < AR; ++a) af[a] = *(const bf16x8*)(&As[cur][rdA + a * 512]);
#pragma unroll
    for (int b = 0; b < AC; ++b) bfv[b] = *(const bf16x8*)(&Bs[cur][rdB + b * 512]);
#pragma unroll
    for (int a = 0; a < AR; ++a)
#pragma unroll
      for (int b = 0; b < AC; ++b) MFMA16(acc[a][b], af[a], bfv[b]);
    __syncthreads();  // drains prefetch + all waves' reads of buf[cur]
  }
  int lr = (lane >> 4) << 2;
  int lc = lane & 15;
#pragma unroll
  for (int a = 0; a < AR; ++a) {
#pragma unroll
    for (int b = 0; b < AC; ++b) {
      int col = n0 + wc * (BN / NWC) + b * 16 + lc;
      float bv = 0.0f;
      if constexpr (BIAS) bv = bias[col];
#pragma unroll
      for (int j = 0; j < 4; ++j) {
        int rowi = m0 + wr * (BM / NWR) + a * 16 + lr + j;
        float v = acc[a][b][j] + bv;
        if constexpr (ACT == 1) v = silu_f(v);
        if constexpr (ACT == 2) v = mish_f(v);
        if constexpr (OUTBF16) Cb[(size_t)rowi * N + col] = __float2bfloat16(v);
        else Cf[(size_t)rowi * N + col] = v;
      }
    }
  }
}

// ---------------- 1-wave 16x16-tile GEMM, direct-from-global (c_kernel pattern) --------
// R12: for tiny-M matmuls (smolgen h/sgf) the block-tiled GEMM leaves CUs idle (h: 8
// blocks). One 64-lane wave per 16x16 output tile; A/B frags straight from global
// (row=fr, k=s4*8); acc is the only dependent chain. ACT=1 silu; f32 out + bias.
template <int ACT>
__global__ __launch_bounds__(64) void gemm_wave16(const bf16* __restrict__ A,
                                                  const bf16* __restrict__ Bt,
                                                  const float* __restrict__ bias,
                                                  float* __restrict__ Cf,
                                                  int N, int K) {
  const int lane = threadIdx.x;
  const int fr = lane & 15, s4 = lane >> 4;
  const int ncols = N >> 4;
  const int rb = blockIdx.x / ncols, cb = blockIdx.x - rb * ncols;
  const int row0 = rb << 4, col0 = cb << 4;
  f32x4 acc = {};
  const bf16* Arow = A + (size_t)(row0 + fr) * K + s4 * 8;
  const bf16* Brow = Bt + (size_t)(col0 + fr) * K + s4 * 8;
  const int nk = K >> 5;
#pragma unroll 8
  for (int kt = 0; kt < nk; ++kt) {
    bf16x8 a = *(const bf16x8*)(Arow + kt * 32);
    bf16x8 b = *(const bf16x8*)(Brow + kt * 32);
    acc = __builtin_amdgcn_mfma_f32_16x16x32_bf16(a, b, acc, 0, 0, 0);
  }
#pragma unroll
  for (int j = 0; j < 4; ++j) {
    int col = col0 + fr;
    float v = acc[j] + bias[col];
    if constexpr (ACT == 1) v = silu_f(v);
    Cf[(size_t)(row0 + s4 * 4 + j) * N + col] = v;
  }
}

// ---------------- c = xb @ Wsc^T : [8192,1024]bf16 @ [32,1024]^T -> bf16 [8192,32] -----
__global__ __launch_bounds__(64) void c_kernel(const bf16* __restrict__ xb,
                                               const bf16* __restrict__ Wsc,
                                               bf16* __restrict__ cout) {
  const int lane = threadIdx.x;
  const int fr = lane & 15, s4 = lane >> 4;
  const int row0 = blockIdx.x * 16;
  f32x4 acc[2] = {};
  const bf16* Arow = xb + (size_t)(row0 + fr) * 1024 + s4 * 8;
  const bf16* B0 = Wsc + (size_t)fr * 1024 + s4 * 8;
  const bf16* B1 = Wsc + (size_t)(16 + fr) * 1024 + s4 * 8;
#pragma unroll 8
  for (int kt = 0; kt < 32; ++kt) {
    bf16x8 a = *(const bf16x8*)(Arow + kt * 32);
    bf16x8 b0 = *(const bf16x8*)(B0 + kt * 32);
    bf16x8 b1 = *(const bf16x8*)(B1 + kt * 32);
    acc[0] = __builtin_amdgcn_mfma_f32_16x16x32_bf16(a, b0, acc[0], 0, 0, 0);
    acc[1] = __builtin_amdgcn_mfma_f32_16x16x32_bf16(a, b1, acc[1], 0, 0, 0);
  }
#pragma unroll
  for (int n2 = 0; n2 < 2; ++n2)
#pragma unroll
    for (int j = 0; j < 4; ++j)
      cout[(size_t)(row0 + s4 * 4 + j) * 32 + n2 * 16 + fr] =
          __float2bfloat16(acc[n2][j]);
}

// ---------------- LN over 256 cols: hb = LN(hpre) -> bf16 ------------------------------
__global__ __launch_bounds__(256) void ln256_kernel(const float* __restrict__ hpre,
                                                    const float* __restrict__ gam,
                                                    const float* __restrict__ bet,
                                                    bf16* __restrict__ hb) {
  __shared__ float rsm[4], rs2[4], st2[2];
  int t = threadIdx.x, row = blockIdx.x;
  float sv = hpre[(size_t)row * 256 + t];
  float s = sv, s2 = sv * sv;
#pragma unroll
  for (int o = 32; o > 0; o >>= 1) { s += __shfl_down(s, o); s2 += __shfl_down(s2, o); }
  if ((t & 63) == 0) { rsm[t >> 6] = s; rs2[t >> 6] = s2; }
  __syncthreads();
  if (t == 0) {
    float a = rsm[0] + rsm[1] + rsm[2] + rsm[3];
    float b2 = rs2[0] + rs2[1] + rs2[2] + rs2[3];
    float m = a * (1.0f / 256.0f);
    st2[0] = m;
    st2[1] = rsqrtf(b2 * (1.0f / 256.0f) - m * m + LN_EPS);
  }
  __syncthreads();
  float y = (sv - st2[0]) * st2[1] * gam[t] + bet[t];
  hb[(size_t)row * 256 + t] = __float2bfloat16(y);
}

// ---------------- LN over 8192 cols (smolgen g) -> bf16 --------------------------------
__global__ __launch_bounds__(1024) void ln8192_kernel(const float* __restrict__ gpre,
                                                      const float* __restrict__ gam,
                                                      const float* __restrict__ bet,
                                                      bf16* __restrict__ gb) {
  __shared__ float rsm[16], rs2[16], st2[2];
  int t = threadIdx.x, row = blockIdx.x;
  const float* p = gpre + (size_t)row * 8192;
  float v[8];
  float s = 0.0f, s2 = 0.0f;
#pragma unroll
  for (int i = 0; i < 8; ++i) {
    v[i] = p[t + i * 1024];
    s += v[i];
    s2 += v[i] * v[i];
  }
#pragma unroll
  for (int o = 32; o > 0; o >>= 1) { s += __shfl_down(s, o); s2 += __shfl_down(s2, o); }
  int lane = t & 63, w = t >> 6;
  if (lane == 0) { rsm[w] = s; rs2[w] = s2; }
  __syncthreads();
  if (t == 0) {
    float a = 0.0f, b2 = 0.0f;
#pragma unroll
    for (int i = 0; i < 16; ++i) { a += rsm[i]; b2 += rs2[i]; }
    float m = a * (1.0f / 8192.0f);
    st2[0] = m;
    st2[1] = rsqrtf(b2 * (1.0f / 8192.0f) - m * m + LN_EPS);
  }
  __syncthreads();
  float m = st2[0], r = st2[1];
#pragma unroll
  for (int i = 0; i < 8; ++i) {
    int n = t + i * 1024;
    gb[(size_t)row * 8192 + n] = __float2bfloat16((v[i] - m) * r * gam[n] + bet[n]);
  }
}

// ---------------- residual + LN over 1024 cols (f32 base, bf16 delta) ------------------
__global__ __launch_bounds__(256) void ln_residual_kernel(const float* __restrict__ base,
                                                          const bf16* __restrict__ delta,
                                                          const float* __restrict__ gam,
                                                          const float* __restrict__ bet,
                                                          float* __restrict__ outf,
                                                          bf16* __restrict__ outb) {
  __shared__ float rsm[4], rs2[4], st2[2];
  int t = threadIdx.x, row = blockIdx.x;
  float4 bv = ((const float4*)(base + (size_t)row * 1024))[t];
  ushort4 du = ((const ushort4*)(delta + (size_t)row * 1024))[t];
  float4 v;
  v.x = bv.x + bfu2f(du.x) * ALPHA_F;
  v.y = bv.y + bfu2f(du.y) * ALPHA_F;
  v.z = bv.z + bfu2f(du.z) * ALPHA_F;
  v.w = bv.w + bfu2f(du.w) * ALPHA_F;
  float s = v.x + v.y + v.z + v.w;
  float s2 = v.x * v.x + v.y * v.y + v.z * v.z + v.w * v.w;
#pragma unroll
  for (int o = 32; o > 0; o >>= 1) { s += __shfl_down(s, o); s2 += __shfl_down(s2, o); }
  if ((t & 63) == 0) { rsm[t >> 6] = s; rs2[t >> 6] = s2; }
  __syncthreads();
  if (t == 0) {
    float a = rsm[0] + rsm[1] + rsm[2] + rsm[3];
    float b2 = rs2[0] + rs2[1] + rs2[2] + rs2[3];
    float m = a * (1.0f / 1024.0f);
    st2[0] = m;
    st2[1] = rsqrtf(b2 * (1.0f / 1024.0f) - m * m + LN_EPS);
  }
  __syncthreads();
  float m = st2[0], r = st2[1];
  float4 g4 = ((const float4*)gam)[t];
  float4 b4 = ((const float4*)bet)[t];
  float4 y;
  y.x = (v.x - m) * r * g4.x + b4.x;
  y.y = (v.y - m) * r * g4.y + b4.y;
  y.z = (v.z - m) * r * g4.z + b4.z;
  y.w = (v.w - m) * r * g4.w + b4.w;
  ((float4*)(outf + (size_t)row * 1024))[t] = y;
  ushort4 o4;
  o4.x = f2bfu(y.x); o4.y = f2bfu(y.y); o4.z = f2bfu(y.z); o4.w = f2bfu(y.w);
  ((ushort4*)(outb + (size_t)row * 1024))[t] = o4;
}

// ---------------- MFMA fused attention per (b,h) ---------------------------------------
__global__ __launch_bounds__(256) void attn_kernel(const bf16* __restrict__ qkv,
                                                   const bf16* __restrict__ sw,
                                                   bf16* __restrict__ avb) {
  __shared__ __align__(16) short Vt[32 * 72];
  __shared__ __align__(16) short Sw[64 * 64];
  __shared__ __align__(16) short Pl[64 * 72];
  const int t = threadIdx.x, lane = t & 63, w = t >> 6;
  const int fr = lane & 15, s4 = lane >> 4;
  const int bh = blockIdx.x, b = bh >> 5, h = bh & 31;
  const size_t qb = (size_t)b * 64 * 3072 + h * 32;
  // stage V transposed: Vt[d][k]
  {
    int k = t >> 2, d0 = (t & 3) * 8;
    bf16x8 v = *(const bf16x8*)(qkv + qb + (size_t)k * 3072 + 2048 + d0);
#pragma unroll
    for (int i = 0; i < 8; ++i) Vt[(d0 + i) * 72 + k] = v[i];
  }
  // stage sw bias [64][64]
  {
    const bf16* swp = sw + (size_t)bh * 4096;
    *(bf16x8*)(Sw + t * 8) = *(const bf16x8*)(swp + t * 8);
    *(bf16x8*)(Sw + 2048 + t * 8) = *(const bf16x8*)(swp + 2048 + t * 8);
  }
  __syncthreads();
  // QK^T: S[16 rows][64 cols] per wave
  f32x4 acc[4] = {};
  {
    bf16x8 aq = *(const bf16x8*)(qkv + qb + (size_t)(16 * w + fr) * 3072 + s4 * 8);
#pragma unroll
    for (int n = 0; n < 4; ++n) {
      bf16x8 bk = *(const bf16x8*)(qkv + qb + (size_t)(n * 16 + fr) * 3072 + 1024 + s4 * 8);
      acc[n] = __builtin_amdgcn_mfma_f32_16x16x32_bf16(aq, bk, acc[n], 0, 0, 0);
    }
  }
  // softmax over k for rows q = 16w + s4*4 + j (cols n*16+fr per lane)
  float rinv[4];
#pragma unroll
  for (int j = 0; j < 4; ++j) {
    int q = 16 * w + s4 * 4 + j;
    float pv[4];
    float mx = -1e30f;
#pragma unroll
    for (int n = 0; n < 4; ++n) {
      float v = acc[n][j] * 0.17677669529663687f +
                __bfloat162float(((const bf16*)Sw)[q * 64 + n * 16 + fr]);
      pv[n] = v;
      mx = fmaxf(mx, v);
    }
    mx = fmaxf(mx, __shfl_xor(mx, 1));
    mx = fmaxf(mx, __shfl_xor(mx, 2));
    mx = fmaxf(mx, __shfl_xor(mx, 4));
    mx = fmaxf(mx, __shfl_xor(mx, 8));
    float sum = 0.0f;
#pragma unroll
    for (int n = 0; n < 4; ++n) {
      float e = __expf(pv[n] - mx);
      sum += e;
      ((bf16*)Pl)[q * 72 + n * 16 + fr] = __float2bfloat16(e);
    }
    sum += __shfl_xor(sum, 1);
    sum += __shfl_xor(sum, 2);
    sum += __shfl_xor(sum, 4);
    sum += __shfl_xor(sum, 8);
    rinv[j] = 1.0f / sum;
  }
  __syncthreads();
  // PV: out[16 rows][32 d] per wave
  f32x4 acc2[2] = {};
#pragma unroll
  for (int kt = 0; kt < 2; ++kt) {
    bf16x8 ap = *(const bf16x8*)(Pl + (16 * w + fr) * 72 + kt * 32 + s4 * 8);
#pragma unroll
    for (int n2 = 0; n2 < 2; ++n2) {
      bf16x8 bv = *(const bf16x8*)(Vt + (n2 * 16 + fr) * 72 + kt * 32 + s4 * 8);
      acc2[n2] = __builtin_amdgcn_mfma_f32_16x16x32_bf16(ap, bv, acc2[n2], 0, 0, 0);
    }
  }
#pragma unroll
  for (int n2 = 0; n2 < 2; ++n2) {
#pragma unroll
    for (int j = 0; j < 4; ++j) {
      int q = 16 * w + s4 * 4 + j;
      int d = n2 * 16 + fr;
      avb[(size_t)(b * 64 + q) * 1024 + h * 32 + d] =
          __float2bfloat16(acc2[n2][j] * rinv[j]);
    }
  }
}

extern "C" void kernel_launch(void* const* d_in, const int* in_sizes, int n_in,
                              void* d_out, int out_size, void* d_ws, size_t ws_size,
                              hipStream_t stream) {
  const float* x_in   = (const float*)d_in[0];
  const float* wq_w   = (const float*)d_in[1];
  const float* wq_b   = (const float*)d_in[2];
  const float* wk_w   = (const float*)d_in[3];
  const float* wk_b   = (const float*)d_in[4];
  const float* wv_w   = (const float*)d_in[5];
  const float* wv_b   = (const float*)d_in[6];
  const float* wo_w   = (const float*)d_in[7];
  const float* wo_b   = (const float*)d_in[8];
  const float* sc_w   = (const float*)d_in[9];
  const float* sh1_w  = (const float*)d_in[10];
  const float* sh1_b  = (const float*)d_in[11];
  const float* sln1_g = (const float*)d_in[12];
  const float* sln1_b = (const float*)d_in[13];
  const float* sgf_w  = (const float*)d_in[14];
  const float* sgf_b  = (const float*)d_in[15];
  const float* sln2_g = (const float*)d_in[16];
  const float* sln2_b = (const float*)d_in[17];
  const float* swg_w  = (const float*)d_in[18];
  const float* ffn1_w = (const float*)d_in[19];
  const float* ffn1_b = (const float*)d_in[20];
  const float* ffn2_w = (const float*)d_in[21];
  const float* ffn2_b = (const float*)d_in[22];
  const float* n1_g   = (const float*)d_in[23];
  const float* n1_b   = (const float*)d_in[24];
  const float* n2_g   = (const float*)d_in[25];
  const float* n2_b   = (const float*)d_in[26];

  char* ws = (char*)d_ws;
  size_t off = 0;
  auto alloc = [&](size_t bytes) -> void* {
    void* p = ws + off;
    off += (bytes + 255) & ~(size_t)255;
    return p;
  };
  bf16*  xb    = (bf16*)alloc(8192ULL * 1024 * 2);
  float* P0    = (float*)alloc(8192ULL * 1024 * 4);
  float* P1    = (float*)alloc(8192ULL * 1024 * 4);
  bf16*  dT    = (bf16*)alloc(8192ULL * 1024 * 2);
  bf16*  Wqkv  = (bf16*)alloc(3072ULL * 1024 * 2);
  float* bqkv  = (float*)alloc(3072ULL * 4);
  bf16*  Wo    = (bf16*)alloc(1024ULL * 1024 * 2);
  bf16*  Wf1   = (bf16*)alloc(1536ULL * 1024 * 2);
  bf16*  Wf2   = (bf16*)alloc(1024ULL * 1536 * 2);
  bf16*  Wsgf  = (bf16*)alloc(8192ULL * 256 * 2);
  bf16*  Wswg  = (bf16*)alloc(4096ULL * 256 * 2);
  bf16*  Wsh1  = (bf16*)alloc(256ULL * 2048 * 2);
  bf16*  Wsc   = (bf16*)alloc(32ULL * 1024 * 2);
  bf16*  qkvb  = (bf16*)alloc(8192ULL * 3072 * 2);
  bf16*  cbuf  = (bf16*)alloc(8192ULL * 32 * 2);
  float* hpre  = (float*)alloc(128ULL * 256 * 4);
  bf16*  hbb   = (bf16*)alloc(128ULL * 256 * 2);
  float* gpre  = (float*)alloc(128ULL * 8192 * 4);
  bf16*  gbb   = (bf16*)alloc(128ULL * 8192 * 2);
  bf16*  swb   = (bf16*)alloc(4096ULL * 4096 * 2);
  bf16*  avb   = (bf16*)alloc(8192ULL * 1024 * 2);
  bf16*  out1b = (bf16*)alloc(8192ULL * 1024 * 2);
  bf16*  f1b   = (bf16*)alloc(8192ULL * 1536 * 2);
  if (off > ws_size) {
    sentinel_k<<<1, 1, 0, stream>>>((float*)d_out);
    return;
  }

  cvt_f32_bf16_k<<<8192, 256, 0, stream>>>(x_in, xb, 8192LL * 1024);

  for (int l = 0; l < 15; ++l) {
    const float* wq   = wq_w + (size_t)l * 1024 * 1024;
    const float* wk   = wk_w + (size_t)l * 1024 * 1024;
    const float* wv   = wv_w + (size_t)l * 1024 * 1024;
    const float* wo   = wo_w + (size_t)l * 1024 * 1024;
    const float* f1w  = ffn1_w + (size_t)l * 1024 * 1536;
    const float* f2w  = ffn2_w + (size_t)l * 1536 * 1024;
    const float* sgf  = sgf_w + (size_t)l * 256 * 8192;
    const float* swg  = swg_w + (size_t)l * 256 * 4096;
    const float* scw  = sc_w + (size_t)l * 1024 * 32;
    const float* sh1w = sh1_w + (size_t)l * 2048 * 256;

    transpose_layer<<<10784, 256, 0, stream>>>(wq, wk, wv, wo, f1w, f2w, sgf, swg, sh1w, scw,
                                               Wqkv, Wo, Wf1, Wf2, Wsgf, Wswg, Wsh1, Wsc);
    pack3_k<<<12, 256, 0, stream>>>(wq_b + l * 1024, wk_b + l * 1024, wv_b + l * 1024, bqkv);

    const float* xc = (l == 0) ? x_in : ((l & 1) ? P0 : P1);
    float* Pout = (l & 1) ? P1 : P0;

    // QKV projection (64x64, 8 blocks/CU — R12)
    gemm_tn<64, 64, 0, true, true><<<6144, 256, 0, stream>>>(xb, Wqkv, bqkv, nullptr, qkvb,
                                                             8192, 3072, 1024);
    // smolgen chain
    c_kernel<<<512, 64, 0, stream>>>(xb, Wsc, cbuf);
    gemm_wave16<1><<<128, 64, 0, stream>>>(cbuf, Wsh1, sh1_b + l * 256, hpre, 256, 2048);
    ln256_kernel<<<128, 256, 0, stream>>>(hpre, sln1_g + l * 256, sln1_b + l * 256, hbb);
    gemm_wave16<1><<<4096, 64, 0, stream>>>(hbb, Wsgf, sgf_b + (size_t)l * 8192, gpre,
                                            8192, 256);
    ln8192_kernel<<<128, 1024, 0, stream>>>(gpre, sln2_g + (size_t)l * 8192,
                                            sln2_b + (size_t)l * 8192, gbb);
    gemm_tn<64, 64, 0, true, false><<<4096, 256, 0, stream>>>(gbb, Wswg, nullptr, nullptr, swb,
                                                              4096, 4096, 256);
    // attention (MFMA)
    attn_kernel<<<4096, 256, 0, stream>>>(qkvb, swb, avb);
    // output projection + LN1 (bf16 delta)
    gemm_tn<64, 64, 0, true, true><<<2048, 256, 0, stream>>>(avb, Wo, wo_b + l * 1024,
                                                             nullptr, dT, 8192, 1024, 1024);
    ln_residual_kernel<<<8192, 256, 0, stream>>>(xc, dT, n1_g + l * 1024, n1_b + l * 1024,
                                                 Pout, out1b);
    // FFN + LN2 (bf16 delta)
    gemm_tn<64, 64, 2, true, true><<<3072, 256, 0, stream>>>(out1b, Wf1, ffn1_b + l * 1536,
                                                             nullptr, f1b, 8192, 1536, 1024);
    gemm_tn<64, 64, 0, true, true><<<2048, 256, 0, stream>>>(f1b, Wf2, ffn2_b + l * 1024,
                                                             nullptr, dT, 8192, 1024, 1536);
    float* xnext = (l == 14) ? (float*)d_out : Pout;
    ln_residual_kernel<<<8192, 256, 0, stream>>>(Pout, dT, n2_g + l * 1024, n2_b + l * 1024,
                                                 xnext, xb);
  }
}

// Round 14
// 5314.549 us; speedup vs baseline: 1.1243x; 1.1243x over previous
//
#include <hip/hip_runtime.h>
#include <hip/hip_bf16.h>

typedef __attribute__((ext_vector_type(8))) short bf16x8;
typedef __attribute__((ext_vector_type(4))) float f32x4;
typedef __hip_bfloat16 bf16;

#define ALPHA_F 0.42728713f
#define LN_EPS 1e-3f

__device__ __forceinline__ float silu_f(float x) { return x / (1.0f + __expf(-x)); }
// mish(x) = x*tanh(ln(1+e^x)) = x*(t^2-1)/(t^2+1), t=1+e^x  (exact rewrite, no tanh/log1p)
__device__ __forceinline__ float mish_f(float x) {
  if (x > 20.0f) return x;
  float t = 1.0f + __expf(x);
  float t2 = t * t;
  return x * (t2 - 1.0f) / (t2 + 1.0f);
}
__device__ __forceinline__ unsigned short f2bfu(float x) {
  bf16 h = __float2bfloat16(x);
  return *(unsigned short*)&h;
}
__device__ __forceinline__ float bfu2f(unsigned short u) {
  unsigned int v = (unsigned int)u << 16;
  return *(float*)&v;
}

// Builtin MFMA: LLVM sees real dataflow -> acc lives in AGPRs.
#define MFMA16(acc, a, b) \
  (acc) = __builtin_amdgcn_mfma_f32_16x16x32_bf16((a), (b), (acc), 0, 0, 0)

#define GLOAD_LDS16(gp, lp)                                                              \
  __builtin_amdgcn_global_load_lds((__attribute__((address_space(1))) void*)(void*)(gp), \
                                   (__attribute__((address_space(3))) void*)(void*)(lp), \
                                   16, 0, 0)

// ---------------- batched per-layer weight transpose: W[K,N] f32 -> Wt[N,K] bf16 -------
__global__ __launch_bounds__(256) void transpose_layer(
    const float* __restrict__ wq, const float* __restrict__ wk, const float* __restrict__ wv,
    const float* __restrict__ wo, const float* __restrict__ f1, const float* __restrict__ f2,
    const float* __restrict__ sgf, const float* __restrict__ swg, const float* __restrict__ sh1,
    const float* __restrict__ scw,
    bf16* __restrict__ Wqkv, bf16* __restrict__ Wo, bf16* __restrict__ Wf1,
    bf16* __restrict__ Wf2, bf16* __restrict__ Wsgf, bf16* __restrict__ Wswg,
    bf16* __restrict__ Wsh1, bf16* __restrict__ Wsc) {
  __shared__ float tile[32][33];
  int b = blockIdx.x;
  const float* W;
  bf16* Wt;
  int K, N, tb;
  if (b < 3072) {
    int m = b >> 10;
    W = (m == 0) ? wq : ((m == 1) ? wk : wv);
    Wt = Wqkv + (size_t)m * 1024 * 1024;
    K = 1024; N = 1024; tb = b & 1023;
  } else if (b < 4096)  { W = wo;  Wt = Wo;   K = 1024; N = 1024; tb = b - 3072; }
  else if (b < 5632)    { W = f1;  Wt = Wf1;  K = 1024; N = 1536; tb = b - 4096; }
  else if (b < 7168)    { W = f2;  Wt = Wf2;  K = 1536; N = 1024; tb = b - 5632; }
  else if (b < 9216)    { W = sgf; Wt = Wsgf; K = 256;  N = 8192; tb = b - 7168; }
  else if (b < 10240)   { W = swg; Wt = Wswg; K = 256;  N = 4096; tb = b - 9216; }
  else if (b < 10752)   { W = sh1; Wt = Wsh1; K = 2048; N = 256;  tb = b - 10240; }
  else                  { W = scw; Wt = Wsc;  K = 1024; N = 32;   tb = b - 10752; }
  int ntx = N >> 5;
  int ty_ = tb / ntx, tx_ = tb - ty_ * ntx;
  int nb = tx_ * 32, kb = ty_ * 32;
  int tx = threadIdx.x & 31, ty = threadIdx.x >> 5;
#pragma unroll
  for (int i = 0; i < 4; ++i)
    tile[ty + i * 8][tx] = W[(size_t)(kb + ty + i * 8) * N + nb + tx];
  __syncthreads();
#pragma unroll
  for (int i = 0; i < 4; ++i)
    Wt[(size_t)(nb + ty + i * 8) * K + kb + tx] = __float2bfloat16(tile[tx][ty + i * 8]);
}

__global__ __launch_bounds__(256) void cvt_f32_bf16_k(const float* __restrict__ in,
                                                      bf16* __restrict__ out, long long n) {
  long long i = ((long long)blockIdx.x * 256 + threadIdx.x) * 4;
  if (i + 3 < n) {
    float4 v = *(const float4*)(in + i);
    out[i + 0] = __float2bfloat16(v.x);
    out[i + 1] = __float2bfloat16(v.y);
    out[i + 2] = __float2bfloat16(v.z);
    out[i + 3] = __float2bfloat16(v.w);
  }
}

__global__ __launch_bounds__(256) void pack3_k(const float* __restrict__ a,
                                               const float* __restrict__ b,
                                               const float* __restrict__ c,
                                               float* __restrict__ o) {
  int i = blockIdx.x * 256 + threadIdx.x;
  if (i < 1024) o[i] = a[i];
  else if (i < 2048) o[i] = b[i - 1024];
  else if (i < 3072) o[i] = c[i - 2048];
}

__global__ __launch_bounds__(1) void sentinel_k(float* __restrict__ o) { o[0] = 1.2345e7f; }

// ---------------- BMxBN bf16 MFMA GEMM, 2-phase double-buffered, XCD-swizzled ----------
// R10-R13 model: latency-bound => throughput ~ blocks/CU, BUT tile traffic must stay
// under L2/HBM budget. 64x64 for N<=1536 GEMMs (8 blocks/CU). QKV (N=3072) MUST stay
// 128x128: at 64x64 its A-panel refetch (48x) blew L2 -> HBM-bound 190MB/127us (R13).
template <int BM, int BN, int ACT, bool OUTBF16, bool BIAS>
__global__ __launch_bounds__(256) void gemm_tn(const bf16* __restrict__ A,
                                               const bf16* __restrict__ Bt,
                                               const float* __restrict__ bias,
                                               float* __restrict__ Cf, bf16* __restrict__ Cb,
                                               int M, int N, int K) {
  constexpr int NWC = (BN == 128) ? 2 : 1;  // waves along N
  constexpr int NWR = 4 / NWC;              // waves along M
  constexpr int AR = BM / (16 * NWR);       // row frags per wave
  constexpr int AC = BN / (16 * NWC);       // col frags per wave
  __shared__ __align__(128) short As[2][BM * 32];
  __shared__ __align__(128) short Bs[2][BN * 32];
  int t = threadIdx.x;
  int lane = t & 63, wave = t >> 6;
  // bijective XCD swizzle (m204)
  int nbx = N / BN;
  int nwg = gridDim.x;
  int q = nwg >> 3, r = nwg & 7;
  int xcd = blockIdx.x & 7, lid = blockIdx.x >> 3;
  int swz = (xcd < r ? xcd * (q + 1) : r * (q + 1) + (xcd - r) * q) + lid;
  int by = swz / nbx, bx = swz - by * nbx;
  int m0 = by * BM, n0 = bx * BN;
  int wr = wave / NWC, wc = wave % NWC;
  int fr = lane & 15;
  int fk = (lane >> 4) << 3;

  f32x4 acc[AR][AC] = {};

  int row0 = t >> 2, ko0 = (t & 3) << 3;

  const bf16* Ag0 = A + (size_t)(m0 + row0) * K + ko0;
  const bf16* Ag1 = A + (size_t)(m0 + 64 + row0) * K + ko0;   // used only if BM==128
  const bf16* Bg0 = Bt + (size_t)(n0 + row0) * K + ko0;
  const bf16* Bg1 = Bt + (size_t)(n0 + 64 + row0) * K + ko0;  // used only if BN==128

  auto stageTo = [&](int buf, int k0) {
    GLOAD_LDS16(Ag0 + k0, &As[buf][wave * 512]);
    if constexpr (BM == 128) GLOAD_LDS16(Ag1 + k0, &As[buf][2048 + wave * 512]);
    GLOAD_LDS16(Bg0 + k0, &Bs[buf][wave * 512]);
    if constexpr (BN == 128) GLOAD_LDS16(Bg1 + k0, &Bs[buf][2048 + wave * 512]);
  };

  int nk = K >> 5;
  stageTo(0, 0);
  __syncthreads();  // vmcnt(0) drain: tile 0 resident

  const int rdA = (wr * (BM / NWR) + fr) * 32 + fk;
  const int rdB = (wc * (BN / NWC) + fr) * 32 + fk;

  for (int kt = 0; kt < nk; ++kt) {
    int cur = kt & 1;
    if (kt + 1 < nk) stageTo(cur ^ 1, (kt + 1) << 5);
    bf16x8 af[AR], bfv[AC];
#pragma unroll
    for (int a = 0; a < AR; ++a) af[a] = *(const bf16x8*)(&As[cur][rdA + a * 512]);
#pragma unroll
    for (int b = 0; b < AC; ++b) bfv[b] = *(const bf16x8*)(&Bs[cur][rdB + b * 512]);
#pragma unroll
    for (int a = 0; a < AR; ++a)
#pragma unroll
      for (int b = 0; b < AC; ++b) MFMA16(acc[a][b], af[a], bfv[b]);
    __syncthreads();  // drains prefetch + all waves' reads of buf[cur]
  }
  int lr = (lane >> 4) << 2;
  int lc = lane & 15;
#pragma unroll
  for (int a = 0; a < AR; ++a) {
#pragma unroll
    for (int b = 0; b < AC; ++b) {
      int col = n0 + wc * (BN / NWC) + b * 16 + lc;
      float bv = 0.0f;
      if constexpr (BIAS) bv = bias[col];
#pragma unroll
      for (int j = 0; j < 4; ++j) {
        int rowi = m0 + wr * (BM / NWR) + a * 16 + lr + j;
        float v = acc[a][b][j] + bv;
        if constexpr (ACT == 1) v = silu_f(v);
        if constexpr (ACT == 2) v = mish_f(v);
        if constexpr (OUTBF16) Cb[(size_t)rowi * N + col] = __float2bfloat16(v);
        else Cf[(size_t)rowi * N + col] = v;
      }
    }
  }
}

// ---------------- 1-wave 16x16-tile GEMM, direct-from-global (c_kernel pattern) --------
template <int ACT>
__global__ __launch_bounds__(64) void gemm_wave16(const bf16* __restrict__ A,
                                                  const bf16* __restrict__ Bt,
                                                  const float* __restrict__ bias,
                                                  float* __restrict__ Cf,
                                                  int N, int K) {
  const int lane = threadIdx.x;
  const int fr = lane & 15, s4 = lane >> 4;
  const int ncols = N >> 4;
  const int rb = blockIdx.x / ncols, cb = blockIdx.x - rb * ncols;
  const int row0 = rb << 4, col0 = cb << 4;
  f32x4 acc = {};
  const bf16* Arow = A + (size_t)(row0 + fr) * K + s4 * 8;
  const bf16* Brow = Bt + (size_t)(col0 + fr) * K + s4 * 8;
  const int nk = K >> 5;
#pragma unroll 8
  for (int kt = 0; kt < nk; ++kt) {
    bf16x8 a = *(const bf16x8*)(Arow + kt * 32);
    bf16x8 b = *(const bf16x8*)(Brow + kt * 32);
    acc = __builtin_amdgcn_mfma_f32_16x16x32_bf16(a, b, acc, 0, 0, 0);
  }
#pragma unroll
  for (int j = 0; j < 4; ++j) {
    int col = col0 + fr;
    float v = acc[j] + bias[col];
    if constexpr (ACT == 1) v = silu_f(v);
    Cf[(size_t)(row0 + s4 * 4 + j) * N + col] = v;
  }
}

// ---------------- c = xb @ Wsc^T : [8192,1024]bf16 @ [32,1024]^T -> bf16 [8192,32] -----
__global__ __launch_bounds__(64) void c_kernel(const bf16* __restrict__ xb,
                                               const bf16* __restrict__ Wsc,
                                               bf16* __restrict__ cout) {
  const int lane = threadIdx.x;
  const int fr = lane & 15, s4 = lane >> 4;
  const int row0 = blockIdx.x * 16;
  f32x4 acc[2] = {};
  const bf16* Arow = xb + (size_t)(row0 + fr) * 1024 + s4 * 8;
  const bf16* B0 = Wsc + (size_t)fr * 1024 + s4 * 8;
  const bf16* B1 = Wsc + (size_t)(16 + fr) * 1024 + s4 * 8;
#pragma unroll 8
  for (int kt = 0; kt < 32; ++kt) {
    bf16x8 a = *(const bf16x8*)(Arow + kt * 32);
    bf16x8 b0 = *(const bf16x8*)(B0 + kt * 32);
    bf16x8 b1 = *(const bf16x8*)(B1 + kt * 32);
    acc[0] = __builtin_amdgcn_mfma_f32_16x16x32_bf16(a, b0, acc[0], 0, 0, 0);
    acc[1] = __builtin_amdgcn_mfma_f32_16x16x32_bf16(a, b1, acc[1], 0, 0, 0);
  }
#pragma unroll
  for (int n2 = 0; n2 < 2; ++n2)
#pragma unroll
    for (int j = 0; j < 4; ++j)
      cout[(size_t)(row0 + s4 * 4 + j) * 32 + n2 * 16 + fr] =
          __float2bfloat16(acc[n2][j]);
}

// ---------------- LN over 256 cols: hb = LN(hpre) -> bf16 ------------------------------
__global__ __launch_bounds__(256) void ln256_kernel(const float* __restrict__ hpre,
                                                    const float* __restrict__ gam,
                                                    const float* __restrict__ bet,
                                                    bf16* __restrict__ hb) {
  __shared__ float rsm[4], rs2[4], st2[2];
  int t = threadIdx.x, row = blockIdx.x;
  float sv = hpre[(size_t)row * 256 + t];
  float s = sv, s2 = sv * sv;
#pragma unroll
  for (int o = 32; o > 0; o >>= 1) { s += __shfl_down(s, o); s2 += __shfl_down(s2, o); }
  if ((t & 63) == 0) { rsm[t >> 6] = s; rs2[t >> 6] = s2; }
  __syncthreads();
  if (t == 0) {
    float a = rsm[0] + rsm[1] + rsm[2] + rsm[3];
    float b2 = rs2[0] + rs2[1] + rs2[2] + rs2[3];
    float m = a * (1.0f / 256.0f);
    st2[0] = m;
    st2[1] = rsqrtf(b2 * (1.0f / 256.0f) - m * m + LN_EPS);
  }
  __syncthreads();
  float y = (sv - st2[0]) * st2[1] * gam[t] + bet[t];
  hb[(size_t)row * 256 + t] = __float2bfloat16(y);
}

// ---------------- LN over 8192 cols (smolgen g) -> bf16 --------------------------------
__global__ __launch_bounds__(1024) void ln8192_kernel(const float* __restrict__ gpre,
                                                      const float* __restrict__ gam,
                                                      const float* __restrict__ bet,
                                                      bf16* __restrict__ gb) {
  __shared__ float rsm[16], rs2[16], st2[2];
  int t = threadIdx.x, row = blockIdx.x;
  const float* p = gpre + (size_t)row * 8192;
  float v[8];
  float s = 0.0f, s2 = 0.0f;
#pragma unroll
  for (int i = 0; i < 8; ++i) {
    v[i] = p[t + i * 1024];
    s += v[i];
    s2 += v[i] * v[i];
  }
#pragma unroll
  for (int o = 32; o > 0; o >>= 1) { s += __shfl_down(s, o); s2 += __shfl_down(s2, o); }
  int lane = t & 63, w = t >> 6;
  if (lane == 0) { rsm[w] = s; rs2[w] = s2; }
  __syncthreads();
  if (t == 0) {
    float a = 0.0f, b2 = 0.0f;
#pragma unroll
    for (int i = 0; i < 16; ++i) { a += rsm[i]; b2 += rs2[i]; }
    float m = a * (1.0f / 8192.0f);
    st2[0] = m;
    st2[1] = rsqrtf(b2 * (1.0f / 8192.0f) - m * m + LN_EPS);
  }
  __syncthreads();
  float m = st2[0], r = st2[1];
#pragma unroll
  for (int i = 0; i < 8; ++i) {
    int n = t + i * 1024;
    gb[(size_t)row * 8192 + n] = __float2bfloat16((v[i] - m) * r * gam[n] + bet[n]);
  }
}

// ---------------- residual + LN over 1024 cols (f32 base, bf16 delta) ------------------
__global__ __launch_bounds__(256) void ln_residual_kernel(const float* __restrict__ base,
                                                          const bf16* __restrict__ delta,
                                                          const float* __restrict__ gam,
                                                          const float* __restrict__ bet,
                                                          float* __restrict__ outf,
                                                          bf16* __restrict__ outb) {
  __shared__ float rsm[4], rs2[4], st2[2];
  int t = threadIdx.x, row = blockIdx.x;
  float4 bv = ((const float4*)(base + (size_t)row * 1024))[t];
  ushort4 du = ((const ushort4*)(delta + (size_t)row * 1024))[t];
  float4 v;
  v.x = bv.x + bfu2f(du.x) * ALPHA_F;
  v.y = bv.y + bfu2f(du.y) * ALPHA_F;
  v.z = bv.z + bfu2f(du.z) * ALPHA_F;
  v.w = bv.w + bfu2f(du.w) * ALPHA_F;
  float s = v.x + v.y + v.z + v.w;
  float s2 = v.x * v.x + v.y * v.y + v.z * v.z + v.w * v.w;
#pragma unroll
  for (int o = 32; o > 0; o >>= 1) { s += __shfl_down(s, o); s2 += __shfl_down(s2, o); }
  if ((t & 63) == 0) { rsm[t >> 6] = s; rs2[t >> 6] = s2; }
  __syncthreads();
  if (t == 0) {
    float a = rsm[0] + rsm[1] + rsm[2] + rsm[3];
    float b2 = rs2[0] + rs2[1] + rs2[2] + rs2[3];
    float m = a * (1.0f / 1024.0f);
    st2[0] = m;
    st2[1] = rsqrtf(b2 * (1.0f / 1024.0f) - m * m + LN_EPS);
  }
  __syncthreads();
  float m = st2[0], r = st2[1];
  float4 g4 = ((const float4*)gam)[t];
  float4 b4 = ((const float4*)bet)[t];
  float4 y;
  y.x = (v.x - m) * r * g4.x + b4.x;
  y.y = (v.y - m) * r * g4.y + b4.y;
  y.z = (v.z - m) * r * g4.z + b4.z;
  y.w = (v.w - m) * r * g4.w + b4.w;
  ((float4*)(outf + (size_t)row * 1024))[t] = y;
  ushort4 o4;
  o4.x = f2bfu(y.x); o4.y = f2bfu(y.y); o4.z = f2bfu(y.z); o4.w = f2bfu(y.w);
  ((ushort4*)(outb + (size_t)row * 1024))[t] = o4;
}

// ---------------- MFMA fused attention per (b,h) ---------------------------------------
__global__ __launch_bounds__(256) void attn_kernel(const bf16* __restrict__ qkv,
                                                   const bf16* __restrict__ sw,
                                                   bf16* __restrict__ avb) {
  __shared__ __align__(16) short Vt[32 * 72];
  __shared__ __align__(16) short Sw[64 * 64];
  __shared__ __align__(16) short Pl[64 * 72];
  const int t = threadIdx.x, lane = t & 63, w = t >> 6;
  const int fr = lane & 15, s4 = lane >> 4;
  const int bh = blockIdx.x, b = bh >> 5, h = bh & 31;
  const size_t qb = (size_t)b * 64 * 3072 + h * 32;
  // stage V transposed: Vt[d][k]
  {
    int k = t >> 2, d0 = (t & 3) * 8;
    bf16x8 v = *(const bf16x8*)(qkv + qb + (size_t)k * 3072 + 2048 + d0);
#pragma unroll
    for (int i = 0; i < 8; ++i) Vt[(d0 + i) * 72 + k] = v[i];
  }
  // stage sw bias [64][64]
  {
    const bf16* swp = sw + (size_t)bh * 4096;
    *(bf16x8*)(Sw + t * 8) = *(const bf16x8*)(swp + t * 8);
    *(bf16x8*)(Sw + 2048 + t * 8) = *(const bf16x8*)(swp + 2048 + t * 8);
  }
  __syncthreads();
  // QK^T: S[16 rows][64 cols] per wave
  f32x4 acc[4] = {};
  {
    bf16x8 aq = *(const bf16x8*)(qkv + qb + (size_t)(16 * w + fr) * 3072 + s4 * 8);
#pragma unroll
    for (int n = 0; n < 4; ++n) {
      bf16x8 bk = *(const bf16x8*)(qkv + qb + (size_t)(n * 16 + fr) * 3072 + 1024 + s4 * 8);
      acc[n] = __builtin_amdgcn_mfma_f32_16x16x32_bf16(aq, bk, acc[n], 0, 0, 0);
    }
  }
  // softmax over k for rows q = 16w + s4*4 + j (cols n*16+fr per lane)
  float rinv[4];
#pragma unroll
  for (int j = 0; j < 4; ++j) {
    int q = 16 * w + s4 * 4 + j;
    float pv[4];
    float mx = -1e30f;
#pragma unroll
    for (int n = 0; n < 4; ++n) {
      float v = acc[n][j] * 0.17677669529663687f +
                __bfloat162float(((const bf16*)Sw)[q * 64 + n * 16 + fr]);
      pv[n] = v;
      mx = fmaxf(mx, v);
    }
    mx = fmaxf(mx, __shfl_xor(mx, 1));
    mx = fmaxf(mx, __shfl_xor(mx, 2));
    mx = fmaxf(mx, __shfl_xor(mx, 4));
    mx = fmaxf(mx, __shfl_xor(mx, 8));
    float sum = 0.0f;
#pragma unroll
    for (int n = 0; n < 4; ++n) {
      float e = __expf(pv[n] - mx);
      sum += e;
      ((bf16*)Pl)[q * 72 + n * 16 + fr] = __float2bfloat16(e);
    }
    sum += __shfl_xor(sum, 1);
    sum += __shfl_xor(sum, 2);
    sum += __shfl_xor(sum, 4);
    sum += __shfl_xor(sum, 8);
    rinv[j] = 1.0f / sum;
  }
  __syncthreads();
  // PV: out[16 rows][32 d] per wave
  f32x4 acc2[2] = {};
#pragma unroll
  for (int kt = 0; kt < 2; ++kt) {
    bf16x8 ap = *(const bf16x8*)(Pl + (16 * w + fr) * 72 + kt * 32 + s4 * 8);
#pragma unroll
    for (int n2 = 0; n2 < 2; ++n2) {
      bf16x8 bv = *(const bf16x8*)(Vt + (n2 * 16 + fr) * 72 + kt * 32 + s4 * 8);
      acc2[n2] = __builtin_amdgcn_mfma_f32_16x16x32_bf16(ap, bv, acc2[n2], 0, 0, 0);
    }
  }
#pragma unroll
  for (int n2 = 0; n2 < 2; ++n2) {
#pragma unroll
    for (int j = 0; j < 4; ++j) {
      int q = 16 * w + s4 * 4 + j;
      int d = n2 * 16 + fr;
      avb[(size_t)(b * 64 + q) * 1024 + h * 32 + d] =
          __float2bfloat16(acc2[n2][j] * rinv[j]);
    }
  }
}

extern "C" void kernel_launch(void* const* d_in, const int* in_sizes, int n_in,
                              void* d_out, int out_size, void* d_ws, size_t ws_size,
                              hipStream_t stream) {
  const float* x_in   = (const float*)d_in[0];
  const float* wq_w   = (const float*)d_in[1];
  const float* wq_b   = (const float*)d_in[2];
  const float* wk_w   = (const float*)d_in[3];
  const float* wk_b   = (const float*)d_in[4];
  const float* wv_w   = (const float*)d_in[5];
  const float* wv_b   = (const float*)d_in[6];
  const float* wo_w   = (const float*)d_in[7];
  const float* wo_b   = (const float*)d_in[8];
  const float* sc_w   = (const float*)d_in[9];
  const float* sh1_w  = (const float*)d_in[10];
  const float* sh1_b  = (const float*)d_in[11];
  const float* sln1_g = (const float*)d_in[12];
  const float* sln1_b = (const float*)d_in[13];
  const float* sgf_w  = (const float*)d_in[14];
  const float* sgf_b  = (const float*)d_in[15];
  const float* sln2_g = (const float*)d_in[16];
  const float* sln2_b = (const float*)d_in[17];
  const float* swg_w  = (const float*)d_in[18];
  const float* ffn1_w = (const float*)d_in[19];
  const float* ffn1_b = (const float*)d_in[20];
  const float* ffn2_w = (const float*)d_in[21];
  const float* ffn2_b = (const float*)d_in[22];
  const float* n1_g   = (const float*)d_in[23];
  const float* n1_b   = (const float*)d_in[24];
  const float* n2_g   = (const float*)d_in[25];
  const float* n2_b   = (const float*)d_in[26];

  char* ws = (char*)d_ws;
  size_t off = 0;
  auto alloc = [&](size_t bytes) -> void* {
    void* p = ws + off;
    off += (bytes + 255) & ~(size_t)255;
    return p;
  };
  bf16*  xb    = (bf16*)alloc(8192ULL * 1024 * 2);
  float* P0    = (float*)alloc(8192ULL * 1024 * 4);
  float* P1    = (float*)alloc(8192ULL * 1024 * 4);
  bf16*  dT    = (bf16*)alloc(8192ULL * 1024 * 2);
  bf16*  Wqkv  = (bf16*)alloc(3072ULL * 1024 * 2);
  float* bqkv  = (float*)alloc(3072ULL * 4);
  bf16*  Wo    = (bf16*)alloc(1024ULL * 1024 * 2);
  bf16*  Wf1   = (bf16*)alloc(1536ULL * 1024 * 2);
  bf16*  Wf2   = (bf16*)alloc(1024ULL * 1536 * 2);
  bf16*  Wsgf  = (bf16*)alloc(8192ULL * 256 * 2);
  bf16*  Wswg  = (bf16*)alloc(4096ULL * 256 * 2);
  bf16*  Wsh1  = (bf16*)alloc(256ULL * 2048 * 2);
  bf16*  Wsc   = (bf16*)alloc(32ULL * 1024 * 2);
  bf16*  qkvb  = (bf16*)alloc(8192ULL * 3072 * 2);
  bf16*  cbuf  = (bf16*)alloc(8192ULL * 32 * 2);
  float* hpre  = (float*)alloc(128ULL * 256 * 4);
  bf16*  hbb   = (bf16*)alloc(128ULL * 256 * 2);
  float* gpre  = (float*)alloc(128ULL * 8192 * 4);
  bf16*  gbb   = (bf16*)alloc(128ULL * 8192 * 2);
  bf16*  swb   = (bf16*)alloc(4096ULL * 4096 * 2);
  bf16*  avb   = (bf16*)alloc(8192ULL * 1024 * 2);
  bf16*  out1b = (bf16*)alloc(8192ULL * 1024 * 2);
  bf16*  f1b   = (bf16*)alloc(8192ULL * 1536 * 2);
  if (off > ws_size) {
    sentinel_k<<<1, 1, 0, stream>>>((float*)d_out);
    return;
  }

  cvt_f32_bf16_k<<<8192, 256, 0, stream>>>(x_in, xb, 8192LL * 1024);

  for (int l = 0; l < 15; ++l) {
    const float* wq   = wq_w + (size_t)l * 1024 * 1024;
    const float* wk   = wk_w + (size_t)l * 1024 * 1024;
    const float* wv   = wv_w + (size_t)l * 1024 * 1024;
    const float* wo   = wo_w + (size_t)l * 1024 * 1024;
    const float* f1w  = ffn1_w + (size_t)l * 1024 * 1536;
    const float* f2w  = ffn2_w + (size_t)l * 1536 * 1024;
    const float* sgf  = sgf_w + (size_t)l * 256 * 8192;
    const float* swg  = swg_w + (size_t)l * 256 * 4096;
    const float* scw  = sc_w + (size_t)l * 1024 * 32;
    const float* sh1w = sh1_w + (size_t)l * 2048 * 256;

    transpose_layer<<<10784, 256, 0, stream>>>(wq, wk, wv, wo, f1w, f2w, sgf, swg, sh1w, scw,
                                               Wqkv, Wo, Wf1, Wf2, Wsgf, Wswg, Wsh1, Wsc);
    pack3_k<<<12, 256, 0, stream>>>(wq_b + l * 1024, wk_b + l * 1024, wv_b + l * 1024, bqkv);

    const float* xc = (l == 0) ? x_in : ((l & 1) ? P0 : P1);
    float* Pout = (l & 1) ? P1 : P0;

    // QKV projection (128x128 — R13: N=3072 too wide for 64x64, HBM-bound there)
    gemm_tn<128, 128, 0, true, true><<<1536, 256, 0, stream>>>(xb, Wqkv, bqkv, nullptr, qkvb,
                                                               8192, 3072, 1024);
    // smolgen chain
    c_kernel<<<512, 64, 0, stream>>>(xb, Wsc, cbuf);
    gemm_wave16<1><<<128, 64, 0, stream>>>(cbuf, Wsh1, sh1_b + l * 256, hpre, 256, 2048);
    ln256_kernel<<<128, 256, 0, stream>>>(hpre, sln1_g + l * 256, sln1_b + l * 256, hbb);
    gemm_wave16<1><<<4096, 64, 0, stream>>>(hbb, Wsgf, sgf_b + (size_t)l * 8192, gpre,
                                            8192, 256);
    ln8192_kernel<<<128, 1024, 0, stream>>>(gpre, sln2_g + (size_t)l * 8192,
                                            sln2_b + (size_t)l * 8192, gbb);
    gemm_tn<64, 64, 0, true, false><<<4096, 256, 0, stream>>>(gbb, Wswg, nullptr, nullptr, swb,
                                                              4096, 4096, 256);
    // attention (MFMA)
    attn_kernel<<<4096, 256, 0, stream>>>(qkvb, swb, avb);
    // output projection + LN1 (bf16 delta)
    gemm_tn<64, 64, 0, true, true><<<2048, 256, 0, stream>>>(avb, Wo, wo_b + l * 1024,
                                                             nullptr, dT, 8192, 1024, 1024);
    ln_residual_kernel<<<8192, 256, 0, stream>>>(xc, dT, n1_g + l * 1024, n1_b + l * 1024,
                                                 Pout, out1b);
    // FFN + LN2 (bf16 delta)
    gemm_tn<64, 64, 2, true, true><<<3072, 256, 0, stream>>>(out1b, Wf1, ffn1_b + l * 1536,
                                                             nullptr, f1b, 8192, 1536, 1024);
    gemm_tn<64, 64, 0, true, true><<<2048, 256, 0, stream>>>(f1b, Wf2, ffn2_b + l * 1024,
                                                             nullptr, dT, 8192, 1024, 1536);
    float* xnext = (l == 14) ? (float*)d_out : Pout;
    ln_residual_kernel<<<8192, 256, 0, stream>>>(Pout, dT, n2_g + l * 1024, n2_b + l * 1024,
                                                 xnext, xb);
  }
}

// Round 16
// 5274.870 us; speedup vs baseline: 1.1328x; 1.0075x over previous
//
#include <hip/hip_runtime.h>
#include <hip/hip_bf16.h>

typedef __attribute__((ext_vector_type(8))) short bf16x8;
typedef __attribute__((ext_vector_type(4))) float f32x4;
typedef __hip_bfloat16 bf16;

#define ALPHA_F 0.42728713f
#define LN_EPS 1e-3f

__device__ __forceinline__ float silu_f(float x) { return x / (1.0f + __expf(-x)); }
// mish(x) = x*tanh(ln(1+e^x)) = x*(t^2-1)/(t^2+1), t=1+e^x  (exact rewrite)
__device__ __forceinline__ float mish_f(float x) {
  if (x > 20.0f) return x;
  float t = 1.0f + __expf(x);
  float t2 = t * t;
  return x * (t2 - 1.0f) / (t2 + 1.0f);
}
__device__ __forceinline__ unsigned short f2bfu(float x) {
  bf16 h = __float2bfloat16(x);
  return *(unsigned short*)&h;
}
__device__ __forceinline__ float bfu2f(unsigned short u) {
  unsigned int v = (unsigned int)u << 16;
  return *(float*)&v;
}

// Builtin MFMA: LLVM sees real dataflow -> acc lives in AGPRs.
#define MFMA16(acc, a, b) \
  (acc) = __builtin_amdgcn_mfma_f32_16x16x32_bf16((a), (b), (acc), 0, 0, 0)

#define GLOAD_LDS16(gp, lp)                                                              \
  __builtin_amdgcn_global_load_lds((__attribute__((address_space(1))) void*)(void*)(gp), \
                                   (__attribute__((address_space(3))) void*)(void*)(lp), \
                                   16, 0, 0)

// ------- batched per-layer weight transpose W[K,N] f32 -> Wt[N,K] bf16 (+bias pack) ----
__global__ __launch_bounds__(256) void transpose_layer(
    const float* __restrict__ wq, const float* __restrict__ wk, const float* __restrict__ wv,
    const float* __restrict__ wo, const float* __restrict__ f1, const float* __restrict__ f2,
    const float* __restrict__ sgf, const float* __restrict__ swg, const float* __restrict__ sh1,
    const float* __restrict__ scw,
    const float* __restrict__ bq, const float* __restrict__ bk, const float* __restrict__ bv,
    bf16* __restrict__ Wqkv, bf16* __restrict__ Wo, bf16* __restrict__ Wf1,
    bf16* __restrict__ Wf2, bf16* __restrict__ Wsgf, bf16* __restrict__ Wswg,
    bf16* __restrict__ Wsh1, bf16* __restrict__ Wsc, float* __restrict__ bqkv) {
  __shared__ float tile[32][33];
  int b = blockIdx.x;
  if (b >= 10784) {  // bias pack: 12 blocks x 256 = 3072 elems
    int i = (b - 10784) * 256 + threadIdx.x;
    if (i < 1024) bqkv[i] = bq[i];
    else if (i < 2048) bqkv[i] = bk[i - 1024];
    else bqkv[i] = bv[i - 2048];
    return;
  }
  const float* W;
  bf16* Wt;
  int K, N, tb;
  if (b < 3072) {
    int m = b >> 10;
    W = (m == 0) ? wq : ((m == 1) ? wk : wv);
    Wt = Wqkv + (size_t)m * 1024 * 1024;
    K = 1024; N = 1024; tb = b & 1023;
  } else if (b < 4096)  { W = wo;  Wt = Wo;   K = 1024; N = 1024; tb = b - 3072; }
  else if (b < 5632)    { W = f1;  Wt = Wf1;  K = 1024; N = 1536; tb = b - 4096; }
  else if (b < 7168)    { W = f2;  Wt = Wf2;  K = 1536; N = 1024; tb = b - 5632; }
  else if (b < 9216)    { W = sgf; Wt = Wsgf; K = 256;  N = 8192; tb = b - 7168; }
  else if (b < 10240)   { W = swg; Wt = Wswg; K = 256;  N = 4096; tb = b - 9216; }
  else if (b < 10752)   { W = sh1; Wt = Wsh1; K = 2048; N = 256;  tb = b - 10240; }
  else                  { W = scw; Wt = Wsc;  K = 1024; N = 32;   tb = b - 10752; }
  int ntx = N >> 5;
  int ty_ = tb / ntx, tx_ = tb - ty_ * ntx;
  int nb = tx_ * 32, kb = ty_ * 32;
  int tx = threadIdx.x & 31, ty = threadIdx.x >> 5;
#pragma unroll
  for (int i = 0; i < 4; ++i)
    tile[ty + i * 8][tx] = W[(size_t)(kb + ty + i * 8) * N + nb + tx];
  __syncthreads();
#pragma unroll
  for (int i = 0; i < 4; ++i)
    Wt[(size_t)(nb + ty + i * 8) * K + kb + tx] = __float2bfloat16(tile[tx][ty + i * 8]);
}

__global__ __launch_bounds__(256) void cvt_f32_bf16_k(const float* __restrict__ in,
                                                      bf16* __restrict__ out, long long n) {
  long long i = ((long long)blockIdx.x * 256 + threadIdx.x) * 4;
  if (i + 3 < n) {
    float4 v = *(const float4*)(in + i);
    out[i + 0] = __float2bfloat16(v.x);
    out[i + 1] = __float2bfloat16(v.y);
    out[i + 2] = __float2bfloat16(v.z);
    out[i + 3] = __float2bfloat16(v.w);
  }
}

__global__ __launch_bounds__(1) void sentinel_k(float* __restrict__ o) { o[0] = 1.2345e7f; }

// ---------------- BMxBN bf16 MFMA GEMM, 2-phase double-buffered, XCD-swizzled ----------
// R10-R13 model: latency-bound => throughput ~ blocks/CU, subject to tile-traffic
// fitting L2/HBM. 64x64 for N<=1536 GEMMs (8 blocks/CU); 128x128 for QKV (N=3072).
template <int BM, int BN, int ACT, bool OUTBF16, bool BIAS>
__global__ __launch_bounds__(256) void gemm_tn(const bf16* __restrict__ A,
                                               const bf16* __restrict__ Bt,
                                               const float* __restrict__ bias,
                                               float* __restrict__ Cf, bf16* __restrict__ Cb,
                                               int M, int N, int K) {
  constexpr int NWC = (BN == 128) ? 2 : 1;  // waves along N
  constexpr int NWR = 4 / NWC;              // waves along M
  constexpr int AR = BM / (16 * NWR);       // row frags per wave
  constexpr int AC = BN / (16 * NWC);       // col frags per wave
  __shared__ __align__(128) short As[2][BM * 32];
  __shared__ __align__(128) short Bs[2][BN * 32];
  int t = threadIdx.x;
  int lane = t & 63, wave = t >> 6;
  // bijective XCD swizzle (m204)
  int nbx = N / BN;
  int nwg = gridDim.x;
  int q = nwg >> 3, r = nwg & 7;
  int xcd = blockIdx.x & 7, lid = blockIdx.x >> 3;
  int swz = (xcd < r ? xcd * (q + 1) : r * (q + 1) + (xcd - r) * q) + lid;
  int by = swz / nbx, bx = swz - by * nbx;
  int m0 = by * BM, n0 = bx * BN;
  int wr = wave / NWC, wc = wave % NWC;
  int fr = lane & 15;
  int fk = (lane >> 4) << 3;

  f32x4 acc[AR][AC] = {};

  int row0 = t >> 2, ko0 = (t & 3) << 3;

  const bf16* Ag0 = A + (size_t)(m0 + row0) * K + ko0;
  const bf16* Ag1 = A + (size_t)(m0 + 64 + row0) * K + ko0;   // used only if BM==128
  const bf16* Bg0 = Bt + (size_t)(n0 + row0) * K + ko0;
  const bf16* Bg1 = Bt + (size_t)(n0 + 64 + row0) * K + ko0;  // used only if BN==128

  auto stageTo = [&](int buf, int k0) {
    GLOAD_LDS16(Ag0 + k0, &As[buf][wave * 512]);
    if constexpr (BM == 128) GLOAD_LDS16(Ag1 + k0, &As[buf][2048 + wave * 512]);
    GLOAD_LDS16(Bg0 + k0, &Bs[buf][wave * 512]);
    if constexpr (BN == 128) GLOAD_LDS16(Bg1 + k0, &Bs[buf][2048 + wave * 512]);
  };

  int nk = K >> 5;
  stageTo(0, 0);
  __syncthreads();  // vmcnt(0) drain: tile 0 resident

  const int rdA = (wr * (BM / NWR) + fr) * 32 + fk;
  const int rdB = (wc * (BN / NWC) + fr) * 32 + fk;

  for (int kt = 0; kt < nk; ++kt) {
    int cur = kt & 1;
    if (kt + 1 < nk) stageTo(cur ^ 1, (kt + 1) << 5);
    bf16x8 af[AR], bfv[AC];
#pragma unroll
    for (int a = 0; a < AR; ++a) af[a] = *(const bf16x8*)(&As[cur][rdA + a * 512]);
#pragma unroll
    for (int b = 0; b < AC; ++b) bfv[b] = *(const bf16x8*)(&Bs[cur][rdB + b * 512]);
#pragma unroll
    for (int a = 0; a < AR; ++a)
#pragma unroll
      for (int b = 0; b < AC; ++b) MFMA16(acc[a][b], af[a], bfv[b]);
    __syncthreads();  // drains prefetch + all waves' reads of buf[cur]
  }
  int lr = (lane >> 4) << 2;
  int lc = lane & 15;
#pragma unroll
  for (int a = 0; a < AR; ++a) {
#pragma unroll
    for (int b = 0; b < AC; ++b) {
      int col = n0 + wc * (BN / NWC) + b * 16 + lc;
      float bv = 0.0f;
      if constexpr (BIAS) bv = bias[col];
#pragma unroll
      for (int j = 0; j < 4; ++j) {
        int rowi = m0 + wr * (BM / NWR) + a * 16 + lr + j;
        float v = acc[a][b][j] + bv;
        if constexpr (ACT == 1) v = silu_f(v);
        if constexpr (ACT == 2) v = mish_f(v);
        if constexpr (OUTBF16) Cb[(size_t)rowi * N + col] = __float2bfloat16(v);
        else Cf[(size_t)rowi * N + col] = v;
      }
    }
  }
}

// ---------------- 1-wave 16x16-tile GEMM, direct-from-global (c_kernel pattern) --------
template <int ACT>
__global__ __launch_bounds__(64) void gemm_wave16(const bf16* __restrict__ A,
                                                  const bf16* __restrict__ Bt,
                                                  const float* __restrict__ bias,
                                                  float* __restrict__ Cf,
                                                  int N, int K) {
  const int lane = threadIdx.x;
  const int fr = lane & 15, s4 = lane >> 4;
  const int ncols = N >> 4;
  const int rb = blockIdx.x / ncols, cb = blockIdx.x - rb * ncols;
  const int row0 = rb << 4, col0 = cb << 4;
  f32x4 acc = {};
  const bf16* Arow = A + (size_t)(row0 + fr) * K + s4 * 8;
  const bf16* Brow = Bt + (size_t)(col0 + fr) * K + s4 * 8;
  const int nk = K >> 5;
#pragma unroll 8
  for (int kt = 0; kt < nk; ++kt) {
    bf16x8 a = *(const bf16x8*)(Arow + kt * 32);
    bf16x8 b = *(const bf16x8*)(Brow + kt * 32);
    acc = __builtin_amdgcn_mfma_f32_16x16x32_bf16(a, b, acc, 0, 0, 0);
  }
#pragma unroll
  for (int j = 0; j < 4; ++j) {
    int col = col0 + fr;
    float v = acc[j] + bias[col];
    if constexpr (ACT == 1) v = silu_f(v);
    Cf[(size_t)(row0 + s4 * 4 + j) * N + col] = v;
  }
}

// ---------------- c = xb @ Wsc^T : [8192,1024]bf16 @ [32,1024]^T -> bf16 [8192,32] -----
__global__ __launch_bounds__(64) void c_kernel(const bf16* __restrict__ xb,
                                               const bf16* __restrict__ Wsc,
                                               bf16* __restrict__ cout) {
  const int lane = threadIdx.x;
  const int fr = lane & 15, s4 = lane >> 4;
  const int row0 = blockIdx.x * 16;
  f32x4 acc[2] = {};
  const bf16* Arow = xb + (size_t)(row0 + fr) * 1024 + s4 * 8;
  const bf16* B0 = Wsc + (size_t)fr * 1024 + s4 * 8;
  const bf16* B1 = Wsc + (size_t)(16 + fr) * 1024 + s4 * 8;
#pragma unroll 8
  for (int kt = 0; kt < 32; ++kt) {
    bf16x8 a = *(const bf16x8*)(Arow + kt * 32);
    bf16x8 b0 = *(const bf16x8*)(B0 + kt * 32);
    bf16x8 b1 = *(const bf16x8*)(B1 + kt * 32);
    acc[0] = __builtin_amdgcn_mfma_f32_16x16x32_bf16(a, b0, acc[0], 0, 0, 0);
    acc[1] = __builtin_amdgcn_mfma_f32_16x16x32_bf16(a, b1, acc[1], 0, 0, 0);
  }
#pragma unroll
  for (int n2 = 0; n2 < 2; ++n2)
#pragma unroll
    for (int j = 0; j < 4; ++j)
      cout[(size_t)(row0 + s4 * 4 + j) * 32 + n2 * 16 + fr] =
          __float2bfloat16(acc[n2][j]);
}

// ---------------- LN over 256 cols: hb = LN(hpre) -> bf16 ------------------------------
__global__ __launch_bounds__(256) void ln256_kernel(const float* __restrict__ hpre,
                                                    const float* __restrict__ gam,
                                                    const float* __restrict__ bet,
                                                    bf16* __restrict__ hb) {
  __shared__ float rsm[4], rs2[4], st2[2];
  int t = threadIdx.x, row = blockIdx.x;
  float sv = hpre[(size_t)row * 256 + t];
  float s = sv, s2 = sv * sv;
#pragma unroll
  for (int o = 32; o > 0; o >>= 1) { s += __shfl_down(s, o); s2 += __shfl_down(s2, o); }
  if ((t & 63) == 0) { rsm[t >> 6] = s; rs2[t >> 6] = s2; }
  __syncthreads();
  if (t == 0) {
    float a = rsm[0] + rsm[1] + rsm[2] + rsm[3];
    float b2 = rs2[0] + rs2[1] + rs2[2] + rs2[3];
    float m = a * (1.0f / 256.0f);
    st2[0] = m;
    st2[1] = rsqrtf(b2 * (1.0f / 256.0f) - m * m + LN_EPS);
  }
  __syncthreads();
  float y = (sv - st2[0]) * st2[1] * gam[t] + bet[t];
  hb[(size_t)row * 256 + t] = __float2bfloat16(y);
}

// ---------------- LN over 8192 cols (smolgen g) -> bf16 --------------------------------
__global__ __launch_bounds__(1024) void ln8192_kernel(const float* __restrict__ gpre,
                                                      const float* __restrict__ gam,
                                                      const float* __restrict__ bet,
                                                      bf16* __restrict__ gb) {
  __shared__ float rsm[16], rs2[16], st2[2];
  int t = threadIdx.x, row = blockIdx.x;
  const float* p = gpre + (size_t)row * 8192;
  float v[8];
  float s = 0.0f, s2 = 0.0f;
#pragma unroll
  for (int i = 0; i < 8; ++i) {
    v[i] = p[t + i * 1024];
    s += v[i];
    s2 += v[i] * v[i];
  }
#pragma unroll
  for (int o = 32; o > 0; o >>= 1) { s += __shfl_down(s, o); s2 += __shfl_down(s2, o); }
  int lane = t & 63, w = t >> 6;
  if (lane == 0) { rsm[w] = s; rs2[w] = s2; }
  __syncthreads();
  if (t == 0) {
    float a = 0.0f, b2 = 0.0f;
#pragma unroll
    for (int i = 0; i < 16; ++i) { a += rsm[i]; b2 += rs2[i]; }
    float m = a * (1.0f / 8192.0f);
    st2[0] = m;
    st2[1] = rsqrtf(b2 * (1.0f / 8192.0f) - m * m + LN_EPS);
  }
  __syncthreads();
  float m = st2[0], r = st2[1];
#pragma unroll
  for (int i = 0; i < 8; ++i) {
    int n = t + i * 1024;
    gb[(size_t)row * 8192 + n] = __float2bfloat16((v[i] - m) * r * gam[n] + bet[n]);
  }
}

// ---------------- residual + LN over 1024 cols (f32 base, bf16 delta) ------------------
// R15 lesson: residual stream MUST stay f32 (bf16 stream -> absmax 0.125 > 0.109).
__global__ __launch_bounds__(256) void ln_residual_kernel(const float* __restrict__ base,
                                                          const bf16* __restrict__ delta,
                                                          const float* __restrict__ gam,
                                                          const float* __restrict__ bet,
                                                          float* __restrict__ outf,
                                                          bf16* __restrict__ outb) {
  __shared__ float rsm[4], rs2[4], st2[2];
  int t = threadIdx.x, row = blockIdx.x;
  float4 bv = ((const float4*)(base + (size_t)row * 1024))[t];
  ushort4 du = ((const ushort4*)(delta + (size_t)row * 1024))[t];
  float4 v;
  v.x = bv.x + bfu2f(du.x) * ALPHA_F;
  v.y = bv.y + bfu2f(du.y) * ALPHA_F;
  v.z = bv.z + bfu2f(du.z) * ALPHA_F;
  v.w = bv.w + bfu2f(du.w) * ALPHA_F;
  float s = v.x + v.y + v.z + v.w;
  float s2 = v.x * v.x + v.y * v.y + v.z * v.z + v.w * v.w;
#pragma unroll
  for (int o = 32; o > 0; o >>= 1) { s += __shfl_down(s, o); s2 += __shfl_down(s2, o); }
  if ((t & 63) == 0) { rsm[t >> 6] = s; rs2[t >> 6] = s2; }
  __syncthreads();
  if (t == 0) {
    float a = rsm[0] + rsm[1] + rsm[2] + rsm[3];
    float b2 = rs2[0] + rs2[1] + rs2[2] + rs2[3];
    float m = a * (1.0f / 1024.0f);
    st2[0] = m;
    st2[1] = rsqrtf(b2 * (1.0f / 1024.0f) - m * m + LN_EPS);
  }
  __syncthreads();
  float m = st2[0], r = st2[1];
  float4 g4 = ((const float4*)gam)[t];
  float4 b4 = ((const float4*)bet)[t];
  float4 y;
  y.x = (v.x - m) * r * g4.x + b4.x;
  y.y = (v.y - m) * r * g4.y + b4.y;
  y.z = (v.z - m) * r * g4.z + b4.z;
  y.w = (v.w - m) * r * g4.w + b4.w;
  ((float4*)(outf + (size_t)row * 1024))[t] = y;
  ushort4 o4;
  o4.x = f2bfu(y.x); o4.y = f2bfu(y.y); o4.z = f2bfu(y.z); o4.w = f2bfu(y.w);
  ((ushort4*)(outb + (size_t)row * 1024))[t] = o4;
}

// ---------------- MFMA fused attention per (b,h) ---------------------------------------
// R15: sw is single-use -> read direct from global (no LDS stage, no extra barrier).
// LDS 42.5KB -> ~14KB lifts occupancy 3 -> 8 blocks/CU (latency-bound regime).
__global__ __launch_bounds__(256) void attn_kernel(const bf16* __restrict__ qkv,
                                                   const bf16* __restrict__ sw,
                                                   bf16* __restrict__ avb) {
  __shared__ __align__(16) short Vt[32 * 72];
  __shared__ __align__(16) short Pl[64 * 72];
  const int t = threadIdx.x, lane = t & 63, w = t >> 6;
  const int fr = lane & 15, s4 = lane >> 4;
  const int bh = blockIdx.x, b = bh >> 5, h = bh & 31;
  const size_t qb = (size_t)b * 64 * 3072 + h * 32;
  // stage V transposed: Vt[d][k]  (consumed after the barrier below)
  {
    int k = t >> 2, d0 = (t & 3) * 8;
    bf16x8 v = *(const bf16x8*)(qkv + qb + (size_t)k * 3072 + 2048 + d0);
#pragma unroll
    for (int i = 0; i < 8; ++i) Vt[(d0 + i) * 72 + k] = v[i];
  }
  // QK^T: S[16 rows][64 cols] per wave
  f32x4 acc[4] = {};
  {
    bf16x8 aq = *(const bf16x8*)(qkv + qb + (size_t)(16 * w + fr) * 3072 + s4 * 8);
#pragma unroll
    for (int n = 0; n < 4; ++n) {
      bf16x8 bk = *(const bf16x8*)(qkv + qb + (size_t)(n * 16 + fr) * 3072 + 1024 + s4 * 8);
      acc[n] = __builtin_amdgcn_mfma_f32_16x16x32_bf16(aq, bk, acc[n], 0, 0, 0);
    }
  }
  // softmax over k for rows q = 16w + s4*4 + j (cols n*16+fr per lane); sw from global
  const bf16* swp = sw + (size_t)bh * 4096;
  float rinv[4];
#pragma unroll
  for (int j = 0; j < 4; ++j) {
    int q = 16 * w + s4 * 4 + j;
    float pv[4];
    float mx = -1e30f;
#pragma unroll
    for (int n = 0; n < 4; ++n) {
      float v = acc[n][j] * 0.17677669529663687f +
                __bfloat162float(swp[q * 64 + n * 16 + fr]);
      pv[n] = v;
      mx = fmaxf(mx, v);
    }
    mx = fmaxf(mx, __shfl_xor(mx, 1));
    mx = fmaxf(mx, __shfl_xor(mx, 2));
    mx = fmaxf(mx, __shfl_xor(mx, 4));
    mx = fmaxf(mx, __shfl_xor(mx, 8));
    float sum = 0.0f;
#pragma unroll
    for (int n = 0; n < 4; ++n) {
      float e = __expf(pv[n] - mx);
      sum += e;
      ((bf16*)Pl)[q * 72 + n * 16 + fr] = __float2bfloat16(e);
    }
    sum += __shfl_xor(sum, 1);
    sum += __shfl_xor(sum, 2);
    sum += __shfl_xor(sum, 4);
    sum += __shfl_xor(sum, 8);
    rinv[j] = 1.0f / sum;
  }
  __syncthreads();  // orders Vt (cross-wave) + Pl writes before PV reads
  // PV: out[16 rows][32 d] per wave
  f32x4 acc2[2] = {};
#pragma unroll
  for (int kt = 0; kt < 2; ++kt) {
    bf16x8 ap = *(const bf16x8*)(Pl + (16 * w + fr) * 72 + kt * 32 + s4 * 8);
#pragma unroll
    for (int n2 = 0; n2 < 2; ++n2) {
      bf16x8 bv = *(const bf16x8*)(Vt + (n2 * 16 + fr) * 72 + kt * 32 + s4 * 8);
      acc2[n2] = __builtin_amdgcn_mfma_f32_16x16x32_bf16(ap, bv, acc2[n2], 0, 0, 0);
    }
  }
#pragma unroll
  for (int n2 = 0; n2 < 2; ++n2) {
#pragma unroll
    for (int j = 0; j < 4; ++j) {
      int q = 16 * w + s4 * 4 + j;
      int d = n2 * 16 + fr;
      avb[(size_t)(b * 64 + q) * 1024 + h * 32 + d] =
          __float2bfloat16(acc2[n2][j] * rinv[j]);
    }
  }
}

extern "C" void kernel_launch(void* const* d_in, const int* in_sizes, int n_in,
                              void* d_out, int out_size, void* d_ws, size_t ws_size,
                              hipStream_t stream) {
  const float* x_in   = (const float*)d_in[0];
  const float* wq_w   = (const float*)d_in[1];
  const float* wq_b   = (const float*)d_in[2];
  const float* wk_w   = (const float*)d_in[3];
  const float* wk_b   = (const float*)d_in[4];
  const float* wv_w   = (const float*)d_in[5];
  const float* wv_b   = (const float*)d_in[6];
  const float* wo_w   = (const float*)d_in[7];
  const float* wo_b   = (const float*)d_in[8];
  const float* sc_w   = (const float*)d_in[9];
  const float* sh1_w  = (const float*)d_in[10];
  const float* sh1_b  = (const float*)d_in[11];
  const float* sln1_g = (const float*)d_in[12];
  const float* sln1_b = (const float*)d_in[13];
  const float* sgf_w  = (const float*)d_in[14];
  const float* sgf_b  = (const float*)d_in[15];
  const float* sln2_g = (const float*)d_in[16];
  const float* sln2_b = (const float*)d_in[17];
  const float* swg_w  = (const float*)d_in[18];
  const float* ffn1_w = (const float*)d_in[19];
  const float* ffn1_b = (const float*)d_in[20];
  const float* ffn2_w = (const float*)d_in[21];
  const float* ffn2_b = (const float*)d_in[22];
  const float* n1_g   = (const float*)d_in[23];
  const float* n1_b   = (const float*)d_in[24];
  const float* n2_g   = (const float*)d_in[25];
  const float* n2_b   = (const float*)d_in[26];

  char* ws = (char*)d_ws;
  size_t off = 0;
  auto alloc = [&](size_t bytes) -> void* {
    void* p = ws + off;
    off += (bytes + 255) & ~(size_t)255;
    return p;
  };
  bf16*  xb    = (bf16*)alloc(8192ULL * 1024 * 2);
  float* P0    = (float*)alloc(8192ULL * 1024 * 4);
  float* P1    = (float*)alloc(8192ULL * 1024 * 4);
  bf16*  dT    = (bf16*)alloc(8192ULL * 1024 * 2);
  bf16*  Wqkv  = (bf16*)alloc(3072ULL * 1024 * 2);
  float* bqkv  = (float*)alloc(3072ULL * 4);
  bf16*  Wo    = (bf16*)alloc(1024ULL * 1024 * 2);
  bf16*  Wf1   = (bf16*)alloc(1536ULL * 1024 * 2);
  bf16*  Wf2   = (bf16*)alloc(1024ULL * 1536 * 2);
  bf16*  Wsgf  = (bf16*)alloc(8192ULL * 256 * 2);
  bf16*  Wswg  = (bf16*)alloc(4096ULL * 256 * 2);
  bf16*  Wsh1  = (bf16*)alloc(256ULL * 2048 * 2);
  bf16*  Wsc   = (bf16*)alloc(32ULL * 1024 * 2);
  bf16*  qkvb  = (bf16*)alloc(8192ULL * 3072 * 2);
  bf16*  cbuf  = (bf16*)alloc(8192ULL * 32 * 2);
  float* hpre  = (float*)alloc(128ULL * 256 * 4);
  bf16*  hbb   = (bf16*)alloc(128ULL * 256 * 2);
  float* gpre  = (float*)alloc(128ULL * 8192 * 4);
  bf16*  gbb   = (bf16*)alloc(128ULL * 8192 * 2);
  bf16*  swb   = (bf16*)alloc(4096ULL * 4096 * 2);
  bf16*  avb   = (bf16*)alloc(8192ULL * 1024 * 2);
  bf16*  out1b = (bf16*)alloc(8192ULL * 1024 * 2);
  bf16*  f1b   = (bf16*)alloc(8192ULL * 1536 * 2);
  if (off > ws_size) {
    sentinel_k<<<1, 1, 0, stream>>>((float*)d_out);
    return;
  }

  cvt_f32_bf16_k<<<8192, 256, 0, stream>>>(x_in, xb, 8192LL * 1024);

  for (int l = 0; l < 15; ++l) {
    const float* wq   = wq_w + (size_t)l * 1024 * 1024;
    const float* wk   = wk_w + (size_t)l * 1024 * 1024;
    const float* wv   = wv_w + (size_t)l * 1024 * 1024;
    const float* wo   = wo_w + (size_t)l * 1024 * 1024;
    const float* f1w  = ffn1_w + (size_t)l * 1024 * 1536;
    const float* f2w  = ffn2_w + (size_t)l * 1536 * 1024;
    const float* sgf  = sgf_w + (size_t)l * 256 * 8192;
    const float* swg  = swg_w + (size_t)l * 256 * 4096;
    const float* scw  = sc_w + (size_t)l * 1024 * 32;
    const float* sh1w = sh1_w + (size_t)l * 2048 * 256;

    transpose_layer<<<10796, 256, 0, stream>>>(wq, wk, wv, wo, f1w, f2w, sgf, swg, sh1w, scw,
                                               wq_b + l * 1024, wk_b + l * 1024,
                                               wv_b + l * 1024,
                                               Wqkv, Wo, Wf1, Wf2, Wsgf, Wswg, Wsh1, Wsc,
                                               bqkv);

    const float* xc = (l == 0) ? x_in : ((l & 1) ? P0 : P1);
    float* Pout = (l & 1) ? P1 : P0;

    // QKV projection (128x128 — R13: N=3072 needs the big tile)
    gemm_tn<128, 128, 0, true, true><<<1536, 256, 0, stream>>>(xb, Wqkv, bqkv, nullptr, qkvb,
                                                               8192, 3072, 1024);
    // smolgen chain
    c_kernel<<<512, 64, 0, stream>>>(xb, Wsc, cbuf);
    gemm_wave16<1><<<128, 64, 0, stream>>>(cbuf, Wsh1, sh1_b + l * 256, hpre, 256, 2048);
    ln256_kernel<<<128, 256, 0, stream>>>(hpre, sln1_g + l * 256, sln1_b + l * 256, hbb);
    gemm_wave16<1><<<4096, 64, 0, stream>>>(hbb, Wsgf, sgf_b + (size_t)l * 8192, gpre,
                                            8192, 256);
    ln8192_kernel<<<128, 1024, 0, stream>>>(gpre, sln2_g + (size_t)l * 8192,
                                            sln2_b + (size_t)l * 8192, gbb);
    gemm_tn<64, 64, 0, true, false><<<4096, 256, 0, stream>>>(gbb, Wswg, nullptr, nullptr, swb,
                                                              4096, 4096, 256);
    // attention (MFMA, sw direct-from-global)
    attn_kernel<<<4096, 256, 0, stream>>>(qkvb, swb, avb);
    // output projection + LN1 (bf16 delta, f32 residual stream)
    gemm_tn<64, 64, 0, true, true><<<2048, 256, 0, stream>>>(avb, Wo, wo_b + l * 1024,
                                                             nullptr, dT, 8192, 1024, 1024);
    ln_residual_kernel<<<8192, 256, 0, stream>>>(xc, dT, n1_g + l * 1024, n1_b + l * 1024,
                                                 Pout, out1b);
    // FFN + LN2
    gemm_tn<64, 64, 2, true, true><<<3072, 256, 0, stream>>>(out1b, Wf1, ffn1_b + l * 1536,
                                                             nullptr, f1b, 8192, 1536, 1024);
    gemm_tn<64, 64, 0, true, true><<<2048, 256, 0, stream>>>(f1b, Wf2, ffn2_b + l * 1024,
                                                             nullptr, dT, 8192, 1024, 1536);
    float* xnext = (l == 14) ? (float*)d_out : Pout;
    ln_residual_kernel<<<8192, 256, 0, stream>>>(Pout, dT, n2_g + l * 1024, n2_b + l * 1024,
                                                 xnext, xb);
  }
}